// Round 1
// baseline (852.783 us; speedup 1.0000x reference)
//
#include <hip/hip_runtime.h>

typedef unsigned short u16;
typedef unsigned int u32;
typedef __attribute__((ext_vector_type(8))) short short8;
typedef __attribute__((ext_vector_type(4))) float f32x4;

// Problem constants
#define N_B 2
#define N_S 1024
#define N_DIN 2048
#define N_DOUT 2048
#define N_H 8
#define N_DK 64
#define N_DV 128
#define N_CONVD 2560
#define N_G 1024
#define N_NH 3584  // CONVD + G

#define C_E2 2.88539008f     // 2/ln2 : tanh(x) = 1 - 2/(2^(C_E2*x)+1)
#define C_E2_INV 0.34657359f // ln2/2

__device__ __forceinline__ u16 f2bf(float f) {
  u32 u = __float_as_uint(f);
  u32 r = (u + 0x7FFFu + ((u >> 16) & 1u)) >> 16;
  return (u16)r;
}
__device__ __forceinline__ float fsigmoid(float x) {
  return __builtin_amdgcn_rcpf(1.f + __builtin_amdgcn_exp2f(-1.44269504f * x));
}
// pack two f32 -> bf16x2 (RNE) in one instruction
__device__ __forceinline__ u32 cvt_pk_bf16(float lo, float hi) {
  u32 r;
  asm("v_cvt_pk_bf16_f32 %0, %1, %2" : "=v"(r) : "v"(lo), "v"(hi));
  return r;
}
// 16-lane-row prefix sum; lane m16==15 holds the row total
__device__ __forceinline__ float row16_prefix_sum(float pr) {
  pr += __int_as_float(__builtin_amdgcn_update_dpp(0, __float_as_int(pr), 0x111, 0xF, 0xF, true));
  pr += __int_as_float(__builtin_amdgcn_update_dpp(0, __float_as_int(pr), 0x112, 0xF, 0xF, true));
  pr += __int_as_float(__builtin_amdgcn_update_dpp(0, __float_as_int(pr), 0x114, 0xF, 0xF, true));
  pr += __int_as_float(__builtin_amdgcn_update_dpp(0, __float_as_int(pr), 0x118, 0xF, 0xF, true));
  return pr;
}

// ---------------- generic f32 -> bf16 convert ----------------
__global__ void cvt_kernel(const float* __restrict__ src, u16* __restrict__ dst, int n) {
  int i4 = (blockIdx.x * 256 + threadIdx.x) * 4;
  if (i4 + 3 < n) {
    float4 v = *(const float4*)&src[i4];
    dst[i4 + 0] = f2bf(v.x);
    dst[i4 + 1] = f2bf(v.y);
    dst[i4 + 2] = f2bf(v.z);
    dst[i4 + 3] = f2bf(v.w);
  }
}

// ---------------- W transpose + pre-scale by 2/ln2: Wt[h][j][v] = c*W[h][v][j] (bf16) -----
__global__ void wtprep_kernel(const float* __restrict__ sw, u16* __restrict__ wtb) {
  int idx = blockIdx.x * 256 + threadIdx.x;  // h*16384 + j*128 + v
  if (idx >= N_H * 128 * 128) return;
  int h = idx >> 14;
  int rem = idx & 16383;
  int j = rem >> 7, v = rem & 127;
  wtb[idx] = f2bf(C_E2 * sw[((size_t)h * 128 + v) * 128 + j]);
}

// ---------------- bf16 NT GEMM: C[M][N] = A[M][K] * B[N][K]^T (+bias) ----------------
__global__ __launch_bounds__(256, 2) void gemm_bt(const u16* __restrict__ A,
                                                  const u16* __restrict__ B,
                                                  const float* __restrict__ bias,
                                                  float* __restrict__ C, int M, int N, int K) {
  const int tid = threadIdx.x;
  const int lane = tid & 63, w = tid >> 6;
  const int u = lane >> 4, m16 = lane & 15;
  const int wm = w & 1, wn = w >> 1;
  const int m0 = blockIdx.y * 128, n0 = blockIdx.x * 128;

  __shared__ __align__(16) u16 As[128 * 32];
  __shared__ __align__(16) u16 Bs[128 * 32];

  f32x4 acc[4][4];
#pragma unroll
  for (int i = 0; i < 4; ++i)
#pragma unroll
    for (int j = 0; j < 4; ++j)
#pragma unroll
      for (int r = 0; r < 4; ++r) acc[i][j][r] = 0.f;

  for (int kk = 0; kk < K; kk += 32) {
#pragma unroll
    for (int q = 0; q < 2; ++q) {
      int chunk = tid + 256 * q;
      int row = chunk >> 2, col = (chunk & 3) * 8;
      *(uint4*)&As[row * 32 + col] = *(const uint4*)&A[(size_t)(m0 + row) * K + kk + col];
      *(uint4*)&Bs[row * 32 + col] = *(const uint4*)&B[(size_t)(n0 + row) * K + kk + col];
    }
    __syncthreads();
    short8 af[4], bfr[4];
#pragma unroll
    for (int i = 0; i < 4; ++i) af[i] = *(const short8*)&As[(64 * wm + 16 * i + m16) * 32 + 8 * u];
#pragma unroll
    for (int i = 0; i < 4; ++i) bfr[i] = *(const short8*)&Bs[(64 * wn + 16 * i + m16) * 32 + 8 * u];
#pragma unroll
    for (int am = 0; am < 4; ++am)
#pragma unroll
      for (int bn = 0; bn < 4; ++bn)
        acc[am][bn] = __builtin_amdgcn_mfma_f32_16x16x32_bf16(af[am], bfr[bn], acc[am][bn], 0, 0, 0);
    __syncthreads();
  }
#pragma unroll
  for (int am = 0; am < 4; ++am)
#pragma unroll
    for (int bn = 0; bn < 4; ++bn) {
      int n = n0 + 64 * wn + 16 * bn + m16;
      float bv = bias ? bias[n] : 0.f;
#pragma unroll
      for (int r = 0; r < 4; ++r) {
        int m = m0 + 64 * wm + 16 * am + 4 * u + r;
        C[(size_t)m * N + n] = acc[am][bn][r] + bv;
      }
    }
}

// ---------------- depthwise causal conv (K=4) + SiLU + scatter to scan layout ----------------
// SCIN[b*8+h][t][320]: q[0,64) k[64,128) g/f[128,192) v[192,320)
// v-slots are pre-scaled by 2/ln2 (folded into the scan's exp2 argument).
__global__ void conv_kernel(const float* __restrict__ h, const float* __restrict__ cw,
                            const float* __restrict__ cb, float* __restrict__ SCIN) {
  int gid = blockIdx.x * 256 + threadIdx.x;
  if (gid >= N_B * N_S * N_CONVD) return;
  int c = gid % N_CONVD;
  int bt = gid / N_CONVD;
  int t = bt & 1023, b = bt >> 10;
  float4 wv = *(const float4*)&cw[c * 4];
  const float* wvp = (const float*)&wv;
  float acc = cb[c];
#pragma unroll
  for (int j = 0; j < 4; ++j) {
    int tt = t - 3 + j;
    if (tt >= 0) acc += wvp[j] * h[((size_t)(b * 1024 + tt)) * N_NH + c];
  }
  float yv = acc * fsigmoid(acc);  // silu
  if (c >= 1024 && c < 2048) yv *= C_E2;  // pre-scale v for the scan
  int hh, off;
  if (c < 512) { hh = c >> 6; off = c & 63; }
  else if (c < 1024) { int cc = c - 512; hh = cc >> 6; off = 64 + (cc & 63); }
  else if (c < 2048) { int cc = c - 1024; hh = cc >> 7; off = 192 + (cc & 127); }
  else { int cc = c - 2048; hh = cc >> 6; off = 128 + (cc & 63); }
  SCIN[(((size_t)(b * 8 + hh)) * 1024 + t) * 320 + off] = yv;
}

// ---------------- k-normalize + forget-gate -> g (in place) ----------------
__global__ void prep2_kernel(float* __restrict__ SCIN, const float* __restrict__ fm,
                             const float* __restrict__ fb) {
  int widx = blockIdx.x * 4 + (threadIdx.x >> 6);  // one wave per (chain, t)
  int lane = threadIdx.x & 63;
  int chain = widx >> 10, t = widx & 1023;
  int hh = chain & 7;
  float* base = SCIN + ((size_t)chain * 1024 + t) * 320;
  float kv = base[64 + lane];
  float s = kv * kv;
#pragma unroll
  for (int m = 1; m < 64; m <<= 1) s += __shfl_xor(s, m, 64);
  float inv = __builtin_amdgcn_rsqf(s + 1e-12f);
  base[64 + lane] = kv * inv;
  float fv = base[128 + lane];
  float scale2 = 2.f * fsigmoid(fm[hh]);
  base[128 + lane] = fsigmoid(scale2 * (fv + fb[hh * 64 + lane]));
}

// ---------------- the sequential RSA scan ----------------
// Grid: 64 WGs = 16 chains x 4 i-groups (16 dk-rows each). 256 threads = 4 waves.
// Wave wv owns j-columns [32wv,32wv+32) as TWO 16-col tiles; lane (u,m16) holds
// S[i=m16][j=32wv+16T+4u+r] in f32. The bf16 S tile (B-operand) in LDS is read ONCE
// per wave and reused by both j-tiles -> half the LDS broadcast traffic of the
// 8-wave version. v and the 2/ln2 exp scale are folded into the MFMA accumulator
// init (Wt and SCIN-v are pre-scaled). The y DPP-reduce/store of step t-1 runs
// after the barrier, inside step t's ds_read latency shadow.
__global__ __launch_bounds__(256, 1) void scan_kernel(const u16* __restrict__ Wtb,
                                                      const float* __restrict__ SCIN,
                                                      float* __restrict__ Ybp) {
  const int tid = threadIdx.x;
  const int lane = tid & 63, wv = tid >> 6;  // wv = 0..3
  const int u = lane >> 4, m16 = lane & 15;
  const int chain = blockIdx.x >> 2;
  const int ig = blockIdx.x & 3;  // dk row group: global i = 16*ig + m16
  const int hh = chain & 7;

  __shared__ __align__(16) u16 Slds[2][16 * 136];  // bf16 S tile, double-buffered

  // A-frags: A[m=m16][k=8u+idx] = Wt[hh][32wv+16T+m16][32kc+8u+idx] (pre-scaled by 2/ln2)
  short8 Wf[2][4];
#pragma unroll
  for (int T = 0; T < 2; ++T) {
    const u16* wb = Wtb + ((size_t)hh * 128 + (32 * wv + 16 * T + m16)) * 128 + 8 * u;
#pragma unroll
    for (int kc = 0; kc < 4; ++kc) Wf[T][kc] = *(const short8*)(wb + 32 * kc);
  }

  for (int x = tid; x < 2 * 16 * 136; x += 256) ((u16*)Slds)[x] = 0;

  const float* scin_c = SCIN + (size_t)chain * 1024 * 320;
  float* ybase = Ybp + ((size_t)(chain * 4 + ig)) * 1024 * 128;

  float Sreg[2][4] = {{0.f, 0.f, 0.f, 0.f}, {0.f, 0.f, 0.f, 0.f}};
  float pp[2][4];  // previous step's q*S partials (pipelined across the barrier)

  // t=0 inputs
  float qv = scin_c[16 * ig + m16];
  float kv = scin_c[64 + 16 * ig + m16];
  float gv = scin_c[128 + 16 * ig + m16];
  f32x4 cv0 = *(const f32x4*)&scin_c[192 + 32 * wv + 4 * u];        // = (2/ln2)*v[j], tile 0
  f32x4 cv1 = *(const f32x4*)&scin_c[192 + 32 * wv + 16 + 4 * u];   // tile 1

  __syncthreads();

  for (int t = 0; t < 1024; ++t) {
    const u16* Sr = Slds[t & 1];
    u16* Sw = Slds[(t + 1) & 1];

    // B-frags first: B[k=8u+idx][n=m16] = S[m16][32kc+8u+idx] (shared by both j-tiles)
    short8 Bf[4];
#pragma unroll
    for (int kc = 0; kc < 4; ++kc)
      Bf[kc] = *(const short8*)&Sr[m16 * 136 + 32 * kc + 8 * u];

    // prefetch t+1 inputs (stay in flight across this step)
    const int tn = (t + 1) & 1023;
    const float* pn = scin_c + (size_t)tn * 320;
    float qn = pn[16 * ig + m16];
    float kn = pn[64 + 16 * ig + m16];
    float gn = pn[128 + 16 * ig + m16];
    f32x4 cn0 = *(const f32x4*)&pn[192 + 32 * wv + 4 * u];
    f32x4 cn1 = *(const f32x4*)&pn[192 + 32 * wv + 16 + 4 * u];

    // pipelined y-reduction + store for step t-1 (fills B-frag read latency)
    if (t) {
#pragma unroll
      for (int T = 0; T < 2; ++T)
#pragma unroll
        for (int r = 0; r < 4; ++r) pp[T][r] = row16_prefix_sum(pp[T][r]);
      if (m16 == 15) {
        f32x4 y0, y1;
#pragma unroll
        for (int r = 0; r < 4; ++r) { y0[r] = pp[0][r]; y1[r] = pp[1][r]; }
        *(f32x4*)(ybase + (size_t)(t - 1) * 128 + 32 * wv + 4 * u) = y0;
        *(f32x4*)(ybase + (size_t)(t - 1) * 128 + 32 * wv + 16 + 4 * u) = y1;
      }
    }

    // X^T MFMAs; acc starts at (2/ln2)*v so acc = (2/ln2)*(S.W + v) = exp2 argument.
    f32x4 a0 = cv0, b0 = {0.f, 0.f, 0.f, 0.f};
    f32x4 a1 = cv1, b1 = {0.f, 0.f, 0.f, 0.f};
    a0 = __builtin_amdgcn_mfma_f32_16x16x32_bf16(Wf[0][0], Bf[0], a0, 0, 0, 0);
    a1 = __builtin_amdgcn_mfma_f32_16x16x32_bf16(Wf[1][0], Bf[0], a1, 0, 0, 0);
    b0 = __builtin_amdgcn_mfma_f32_16x16x32_bf16(Wf[0][1], Bf[1], b0, 0, 0, 0);
    b1 = __builtin_amdgcn_mfma_f32_16x16x32_bf16(Wf[1][1], Bf[1], b1, 0, 0, 0);
    a0 = __builtin_amdgcn_mfma_f32_16x16x32_bf16(Wf[0][2], Bf[2], a0, 0, 0, 0);
    a1 = __builtin_amdgcn_mfma_f32_16x16x32_bf16(Wf[1][2], Bf[2], a1, 0, 0, 0);
    b0 = __builtin_amdgcn_mfma_f32_16x16x32_bf16(Wf[0][3], Bf[3], b0, 0, 0, 0);
    b1 = __builtin_amdgcn_mfma_f32_16x16x32_bf16(Wf[1][3], Bf[3], b1, 0, 0, 0);

    // S update + new partials: tanh(x) = 1 - 2/(2^arg + 1), arg already in acc
#pragma unroll
    for (int r = 0; r < 4; ++r) {
      float e0 = __builtin_amdgcn_exp2f(a0[r] + b0[r]);
      float c0 = __builtin_fmaf(-2.f, __builtin_amdgcn_rcpf(e0 + 1.f), 1.f);
      Sreg[0][r] = __builtin_fmaf(gv, Sreg[0][r], kv * c0);
      pp[0][r] = qv * Sreg[0][r];
      float e1 = __builtin_amdgcn_exp2f(a1[r] + b1[r]);
      float c1 = __builtin_fmaf(-2.f, __builtin_amdgcn_rcpf(e1 + 1.f), 1.f);
      Sreg[1][r] = __builtin_fmaf(gv, Sreg[1][r], kv * c1);
      pp[1][r] = qv * Sreg[1][r];
    }

    // bf16 S tile for next step's B operand (wave-exclusive j-columns)
    uint2 w0, w1;
    w0.x = cvt_pk_bf16(Sreg[0][0], Sreg[0][1]);
    w0.y = cvt_pk_bf16(Sreg[0][2], Sreg[0][3]);
    w1.x = cvt_pk_bf16(Sreg[1][0], Sreg[1][1]);
    w1.y = cvt_pk_bf16(Sreg[1][2], Sreg[1][3]);
    *(uint2*)&Sw[m16 * 136 + 32 * wv + 4 * u] = w0;
    *(uint2*)&Sw[m16 * 136 + 32 * wv + 16 + 4 * u] = w1;

    // LDS-only barrier: global stores/loads stay in flight (no vmcnt drain)
    asm volatile("s_waitcnt lgkmcnt(0)\n\ts_barrier" ::: "memory");

    qv = qn; kv = kn; gv = gn; cv0 = cn0; cv1 = cn1;
  }

  // epilogue: y for t=1023
#pragma unroll
  for (int T = 0; T < 2; ++T)
#pragma unroll
    for (int r = 0; r < 4; ++r) pp[T][r] = row16_prefix_sum(pp[T][r]);
  if (m16 == 15) {
    f32x4 y0, y1;
#pragma unroll
    for (int r = 0; r < 4; ++r) { y0[r] = pp[0][r]; y1[r] = pp[1][r]; }
    *(f32x4*)(ybase + (size_t)1023 * 128 + 32 * wv + 4 * u) = y0;
    *(f32x4*)(ybase + (size_t)1023 * 128 + 32 * wv + 16 + 4 * u) = y1;
  }
}

// ---------------- sum y partials, (y + v*D)*silu(gate), RMSNorm, *g_w -> bf16 ----------------
__global__ __launch_bounds__(256, 2) void post_kernel(const float* __restrict__ Ybp,
                                                      const float* __restrict__ SCIN,
                                                      const float* __restrict__ h,
                                                      const float* __restrict__ Dp,
                                                      const float* __restrict__ gwv,
                                                      u16* __restrict__ Zb) {
  const int bt = blockIdx.x;
  const int b = bt >> 10, t = bt & 1023;
  const int lane = threadIdx.x & 63, wvi = threadIdx.x >> 6;
  float z[4];
  float ss = 0.f;
#pragma unroll
  for (int c = 0; c < 4; ++c) {
    int j = threadIdx.x + 256 * c;
    int head = j >> 7, dv = j & 127;
    int chain = b * 8 + head;
    float y = 0.f;
#pragma unroll
    for (int igx = 0; igx < 4; ++igx)
      y += Ybp[(((size_t)(chain * 4 + igx)) * 1024 + t) * 128 + dv];
    float v = SCIN[((size_t)chain * 1024 + t) * 320 + 192 + dv];  // = (2/ln2)*v_true
    float gate = h[((size_t)(b * 1024 + t)) * N_NH + 2560 + j];
    float zz = (y + v * (Dp[j] * C_E2_INV)) * (gate * fsigmoid(gate));
    z[c] = zz;
    ss += zz * zz;
  }
#pragma unroll
  for (int m = 1; m < 64; m <<= 1) ss += __shfl_xor(ss, m, 64);
  __shared__ float red[4];
  if (lane == 0) red[wvi] = ss;
  __syncthreads();
  float tot = red[0] + red[1] + red[2] + red[3];
  float scale = __builtin_amdgcn_rsqf(tot * (1.f / 1024.f) + 1e-6f);
#pragma unroll
  for (int c = 0; c < 4; ++c) {
    int j = threadIdx.x + 256 * c;
    Zb[(size_t)(b * 1024 + t) * 1024 + j] = f2bf(z[c] * scale * gwv[j]);
  }
}

extern "C" void kernel_launch(void* const* d_in, const int* in_sizes, int n_in,
                              void* d_out, int out_size, void* d_ws, size_t ws_size,
                              hipStream_t stream) {
  const float* x    = (const float*)d_in[0];
  const float* w_in = (const float*)d_in[1];
  const float* b_in = (const float*)d_in[2];
  const float* cw   = (const float*)d_in[3];
  const float* cb   = (const float*)d_in[4];
  const float* Dp   = (const float*)d_in[5];
  const float* sw   = (const float*)d_in[6];
  const float* fm   = (const float*)d_in[7];
  const float* fb   = (const float*)d_in[8];
  const float* gwv  = (const float*)d_in[9];
  const float* wo   = (const float*)d_in[10];
  float* out = (float*)d_out;

  char* p = (char*)d_ws;
  auto alloc = [&](size_t bytes) {
    char* r = p;
    p += (bytes + 255) & ~(size_t)255;
    return r;
  };
  u16* xb    = (u16*)alloc((size_t)2048 * 2048 * 2);
  u16* wib   = (u16*)alloc((size_t)3584 * 2048 * 2);
  u16* wob   = (u16*)alloc((size_t)2048 * 1024 * 2);
  u16* wtb   = (u16*)alloc((size_t)8 * 128 * 128 * 2);
  float* hbf = (float*)alloc((size_t)2048 * 3584 * 4);
  float* scin= (float*)alloc((size_t)16 * 1024 * 320 * 4);
  float* ybp = (float*)alloc((size_t)64 * 1024 * 128 * 4);
  u16* zb    = (u16*)alloc((size_t)2048 * 1024 * 2);

  cvt_kernel<<<4096, 256, 0, stream>>>(x, xb, 2048 * 2048);
  cvt_kernel<<<7168, 256, 0, stream>>>(w_in, wib, 3584 * 2048);
  cvt_kernel<<<2048, 256, 0, stream>>>(wo, wob, 2048 * 1024);
  wtprep_kernel<<<512, 256, 0, stream>>>(sw, wtb);

  // h = x @ w_in^T + b_in
  gemm_bt<<<dim3(3584 / 128, 2048 / 128), 256, 0, stream>>>(xb, wib, b_in, hbf, 2048, 3584, 2048);

  conv_kernel<<<(N_B * N_S * N_CONVD) / 256, 256, 0, stream>>>(hbf, cw, cb, scin);
  prep2_kernel<<<(16 * 1024) / 4, 256, 0, stream>>>(scin, fm, fb);

  scan_kernel<<<64, 256, 0, stream>>>(wtb, scin, ybp);

  post_kernel<<<2048, 256, 0, stream>>>(ybp, scin, hbf, Dp, gwv, zb);

  // out = z @ w_out^T
  gemm_bt<<<dim3(2048 / 128, 2048 / 128), 256, 0, stream>>>(zb, wob, nullptr, out, 2048, 2048, 1024);
}